// Round 1
// baseline (463.744 us; speedup 1.0000x reference)
//
#include <hip/hip_runtime.h>
#include <hip/hip_bf16.h>

#define B_  4
#define S_  4096
#define H_  1024
#define DI_ 1280
#define DI2_ 2560
#define E_  3
#define NC_ 64
#define CL_ 64
#define EPS_ 1e-6f

typedef unsigned short ushort_t;
typedef __attribute__((ext_vector_type(8))) __bf16 bf16x8;
typedef __attribute__((ext_vector_type(4))) float f32x4;

__device__ inline ushort_t f2bf(float f) {
    union { float f; unsigned u; } v; v.f = f;
    unsigned r = v.u + 0x7fffu + ((v.u >> 16) & 1u);
    return (ushort_t)(r >> 16);
}
__device__ inline float bf2f(ushort_t s) {
    union { unsigned u; float f; } v; v.u = ((unsigned)s) << 16;
    return v.f;
}
__device__ inline float sigmoidf_(float x) { return 1.0f / (1.0f + __expf(-x)); }

__device__ inline void gld16(const void* g, void* l) {
    __builtin_amdgcn_global_load_lds(
        (const __attribute__((address_space(1))) void*)g,
        (__attribute__((address_space(3))) void*)l, 16, 0, 0);
}

// ---------------- Kernel A: RMSNorm + pooled partials ----------------
// grid (S/16, B), block 256. Each block: 16 rows of one batch.
__global__ __launch_bounds__(256) void rmsnorm_kernel(
    const float* __restrict__ in, const float* __restrict__ nw,
    ushort_t* __restrict__ xbf, float* __restrict__ partial)
{
    int g = blockIdx.x, b = blockIdx.y;
    int tid = threadIdx.x, lane = tid & 63, w = tid >> 6;
    int s0 = g * 16;
    const float4* inb = (const float4*)(in + ((size_t)b * S_ + s0) * H_);
    float4 rows[16];
    float ss[16];
#pragma unroll
    for (int r = 0; r < 16; r++) {
        float4 v = inb[(size_t)r * (H_ / 4) + tid];
        rows[r] = v;
        ss[r] = v.x * v.x + v.y * v.y + v.z * v.z + v.w * v.w;
    }
#pragma unroll
    for (int r = 0; r < 16; r++) {
        float s = ss[r];
        s += __shfl_down(s, 32); s += __shfl_down(s, 16); s += __shfl_down(s, 8);
        s += __shfl_down(s, 4);  s += __shfl_down(s, 2);  s += __shfl_down(s, 1);
        ss[r] = s;
    }
    __shared__ float red[16][4];
    __shared__ float scl[16];
    if (lane == 0) {
#pragma unroll
        for (int r = 0; r < 16; r++) red[r][w] = ss[r];
    }
    __syncthreads();
    if (tid < 16) {
        float t = red[tid][0] + red[tid][1] + red[tid][2] + red[tid][3];
        scl[tid] = rsqrtf(t * (1.0f / H_) + EPS_);
    }
    __syncthreads();
    float4 nw4 = ((const float4*)nw)[tid];
    float4 pacc = {0.f, 0.f, 0.f, 0.f};
    ushort_t* xrow = xbf + ((size_t)b * S_ + s0) * H_;
#pragma unroll
    for (int r = 0; r < 16; r++) {
        float sc = scl[r];
        float4 v = rows[r];
        v.x = v.x * sc * nw4.x; v.y = v.y * sc * nw4.y;
        v.z = v.z * sc * nw4.z; v.w = v.w * sc * nw4.w;
        ushort4 u; u.x = f2bf(v.x); u.y = f2bf(v.y); u.z = f2bf(v.z); u.w = f2bf(v.w);
        *(ushort4*)(xrow + (size_t)r * H_ + tid * 4) = u;
        pacc.x += v.x; pacc.y += v.y; pacc.z += v.z; pacc.w += v.w;
    }
    float4* pp = (float4*)(partial + ((size_t)(b * 256 + g)) * H_);
    pp[tid] = pacc;
}

// ---------------- Kernel B: router softmax + bias mixing + aux ----------------
// grid (B), block 256
__global__ __launch_bounds__(256) void router_kernel(
    const float* __restrict__ partial, const float* __restrict__ rw,
    const float* __restrict__ rb, const float* __restrict__ b_in,
    const float* __restrict__ b_out, float* __restrict__ probs,
    float* __restrict__ bi, float* __restrict__ bo, float* __restrict__ aux)
{
    int b = blockIdx.x;
    int tid = threadIdx.x, lane = tid & 63, w = tid >> 6;
    float4 acc = {0.f, 0.f, 0.f, 0.f};
    const float4* pp = (const float4*)partial;
    for (int g = 0; g < 256; g++) {
        float4 v = pp[((size_t)(b * 256 + g)) * (H_ / 4) + tid];
        acc.x += v.x; acc.y += v.y; acc.z += v.z; acc.w += v.w;
    }
    const float inv_s = 1.0f / (float)S_;
    float a4[4] = {acc.x * inv_s, acc.y * inv_s, acc.z * inv_s, acc.w * inv_s};
    float le[3] = {0.f, 0.f, 0.f};
    int h0 = tid * 4;
#pragma unroll
    for (int j = 0; j < 4; j++) {
        float p = a4[j];
        le[0] += p * rw[(size_t)(h0 + j) * 3 + 0];
        le[1] += p * rw[(size_t)(h0 + j) * 3 + 1];
        le[2] += p * rw[(size_t)(h0 + j) * 3 + 2];
    }
#pragma unroll
    for (int e = 0; e < 3; e++) {
        float s = le[e];
        s += __shfl_down(s, 32); s += __shfl_down(s, 16); s += __shfl_down(s, 8);
        s += __shfl_down(s, 4);  s += __shfl_down(s, 2);  s += __shfl_down(s, 1);
        le[e] = s;
    }
    __shared__ float red[4][3];
    __shared__ float pr[3];
    if (lane == 0) { red[w][0] = le[0]; red[w][1] = le[1]; red[w][2] = le[2]; }
    __syncthreads();
    if (tid == 0) {
        float l0 = red[0][0] + red[1][0] + red[2][0] + red[3][0] + rb[0];
        float l1 = red[0][1] + red[1][1] + red[2][1] + red[3][1] + rb[1];
        float l2 = red[0][2] + red[1][2] + red[2][2] + red[3][2] + rb[2];
        float m = fmaxf(l0, fmaxf(l1, l2));
        float e0 = __expf(l0 - m), e1 = __expf(l1 - m), e2 = __expf(l2 - m);
        float inv = 1.0f / (e0 + e1 + e2);
        pr[0] = e0 * inv; pr[1] = e1 * inv; pr[2] = e2 * inv;
    }
    __syncthreads();
    if (tid < 3) probs[b * 3 + tid] = pr[tid];
    float p0 = pr[0], p1 = pr[1], p2 = pr[2];
    for (int n = tid; n < DI2_; n += 256)
        bi[(size_t)b * DI2_ + n] = p0 * b_in[n] + p1 * b_in[DI2_ + n] + p2 * b_in[2 * DI2_ + n];
    for (int n = tid; n < H_; n += 256)
        bo[(size_t)b * H_ + n] = p0 * b_out[n] + p1 * b_out[H_ + n] + p2 * b_out[2 * H_ + n];
    if (b == 0 && tid == 0) *aux = 0.0f;
}

// ---------------- Kernel C: weight mix + transpose ----------------
// src: (E, K, N) fp32. dst: (B, N, K) bf16.  grid (K/64, N/64, B), block 256
__global__ __launch_bounds__(256) void mix_kernel(
    const float* __restrict__ wsrc, const float* __restrict__ probs,
    ushort_t* __restrict__ dst, int K, int N)
{
    int kt = blockIdx.x, nt = blockIdx.y, b = blockIdx.z;
    float p0 = probs[b * 3 + 0], p1 = probs[b * 3 + 1], p2 = probs[b * 3 + 2];
    __shared__ float T[64][65];
    int tid = threadIdx.x;
    int c = tid & 63, rr = tid >> 6;
    const float* w0 = wsrc;
    const float* w1 = wsrc + (size_t)K * N;
    const float* w2 = wsrc + 2 * (size_t)K * N;
    int k0 = kt * 64, n0 = nt * 64;
#pragma unroll
    for (int pass = 0; pass < 16; pass++) {
        int r = pass * 4 + rr;
        size_t idx = (size_t)(k0 + r) * N + n0 + c;
        T[r][c] = p0 * w0[idx] + p1 * w1[idx] + p2 * w2[idx];
    }
    __syncthreads();
    ushort_t* db = dst + (size_t)b * N * K;
#pragma unroll
    for (int pass = 0; pass < 16; pass++) {
        int j = pass * 4 + rr;
        db[(size_t)(n0 + j) * K + k0 + c] = f2bf(T[c][j]);
    }
}

// ---------------- GEMM: C(MxN) = A(MxK bf16) @ Bt(NxK bf16)^T ----------------
// MODE 0: epilogue -> z/ht bf16 (GRU gates).  MODE 1: epilogue -> out fp32 (+bias+residual)
template <int MODE>
__global__ __launch_bounds__(256, 2) void gemm_bt(
    const ushort_t* __restrict__ Aall, const ushort_t* __restrict__ Btall,
    int M, int N, int K,
    const float* __restrict__ biasAll,
    const float* __restrict__ resAll, float* __restrict__ outAll,
    ushort_t* __restrict__ htAll, ushort_t* __restrict__ zAll, int DIv)
{
    __shared__ ushort_t As[128 * 32];
    __shared__ ushort_t Bs[128 * 32];
    int b = blockIdx.z;
    const ushort_t* A = Aall + (size_t)b * M * K;
    const ushort_t* Bt = Btall + (size_t)b * N * K;
    int tid = threadIdx.x, lane = tid & 63, w = tid >> 6;
    int mblk = blockIdx.x * 128, nblk = blockIdx.y * 128;

    int srow = lane >> 2;
    int scol = (lane & 3) * 8;
    const ushort_t* ga0 = A + (size_t)(mblk + (w * 2 + 0) * 16 + srow) * K + scol;
    const ushort_t* ga1 = A + (size_t)(mblk + (w * 2 + 1) * 16 + srow) * K + scol;
    const ushort_t* gb0 = Bt + (size_t)(nblk + (w * 2 + 0) * 16 + srow) * K + scol;
    const ushort_t* gb1 = Bt + (size_t)(nblk + (w * 2 + 1) * 16 + srow) * K + scol;
    ushort_t* la0 = &As[(w * 2 + 0) * 512 + lane * 8];
    ushort_t* la1 = &As[(w * 2 + 1) * 512 + lane * 8];
    ushort_t* lb0 = &Bs[(w * 2 + 0) * 512 + lane * 8];
    ushort_t* lb1 = &Bs[(w * 2 + 1) * 512 + lane * 8];

    f32x4 acc[4][4] = {};
    int wy = w & 1, wx = w >> 1;
    int q = lane >> 4;
    int ml = lane & 15;
    int aoff0 = (wy * 64 + ml) * 32 + q * 8;
    int boff0 = (wx * 64 + ml) * 32 + q * 8;

    for (int k0 = 0; k0 < K; k0 += 32) {
        gld16(ga0, la0); gld16(ga1, la1);
        gld16(gb0, lb0); gld16(gb1, lb1);
        ga0 += 32; ga1 += 32; gb0 += 32; gb1 += 32;
        __syncthreads();
        bf16x8 af[4], bfr[4];
#pragma unroll
        for (int i = 0; i < 4; i++) af[i] = *(const bf16x8*)&As[aoff0 + i * 16 * 32];
#pragma unroll
        for (int i = 0; i < 4; i++) bfr[i] = *(const bf16x8*)&Bs[boff0 + i * 16 * 32];
#pragma unroll
        for (int mi = 0; mi < 4; mi++)
#pragma unroll
            for (int ni = 0; ni < 4; ni++)
                acc[mi][ni] = __builtin_amdgcn_mfma_f32_16x16x32_bf16(af[mi], bfr[ni], acc[mi][ni], 0, 0, 0);
        __syncthreads();
    }

    int mbase = mblk + wy * 64 + q * 4;
    int nbase = nblk + wx * 64 + ml;
    const float* bias = biasAll + (size_t)b * N;
    if (MODE == 0) {
        bool isgate = (nblk >= DIv);
        ushort_t* dst = (isgate ? zAll : htAll) + (size_t)b * (size_t)M * DIv;
#pragma unroll
        for (int ni = 0; ni < 4; ni++) {
            int n = nbase + ni * 16;
            float bv = bias[n];
            int ncol = isgate ? (n - DIv) : n;
#pragma unroll
            for (int mi = 0; mi < 4; mi++) {
                int m = mbase + mi * 16;
#pragma unroll
                for (int r = 0; r < 4; r++) {
                    float v = acc[mi][ni][r] + bv;
                    float res;
                    if (isgate) res = sigmoidf_(v);
                    else res = (v >= 0.f) ? (v + 0.5f) : sigmoidf_(v);
                    dst[(size_t)(m + r) * DIv + ncol] = f2bf(res);
                }
            }
        }
    } else {
        const float* resb = resAll + (size_t)b * (size_t)M * N;
        float* outp = outAll + (size_t)b * (size_t)M * N;
#pragma unroll
        for (int ni = 0; ni < 4; ni++) {
            int n = nbase + ni * 16;
            float bv = bias[n];
#pragma unroll
            for (int mi = 0; mi < 4; mi++) {
                int m = mbase + mi * 16;
#pragma unroll
                for (int r = 0; r < 4; r++) {
                    size_t idx = (size_t)(m + r) * N + n;
                    outp[idx] = acc[mi][ni][r] + bv + resb[idx];
                }
            }
        }
    }
}

// ---------------- Scan phase 1: per-chunk affine composition ----------------
// grid (DI/256, NC, B), block 256
__global__ __launch_bounds__(256) void scan_phase1(
    const ushort_t* __restrict__ zb, const ushort_t* __restrict__ hb,
    float* __restrict__ cA, float* __restrict__ cB)
{
    int d = blockIdx.x * 256 + threadIdx.x;
    int c = blockIdx.y, b = blockIdx.z;
    size_t base = ((size_t)b * S_ + (size_t)c * CL_) * DI_ + d;
    float A = 1.f, Bc = 0.f;
    for (int t = 0; t < CL_; t++) {
        float z = bf2f(zb[base + (size_t)t * DI_]);
        float h = bf2f(hb[base + (size_t)t * DI_]);
        float a = 1.f - z;
        A *= a;
        Bc = a * Bc + z * h;
    }
    size_t o = ((size_t)b * NC_ + c) * DI_ + d;
    cA[o] = A;
    cB[o] = Bc;
}

// ---------------- Scan phase 2: sequential chunk scan + new_state ----------------
// grid (B*DI/256), block 256
__global__ __launch_bounds__(256) void scan_phase2(
    const float* __restrict__ cA, const float* __restrict__ cB,
    float* __restrict__ h0buf, float* __restrict__ ns)
{
    int g = blockIdx.x * 256 + threadIdx.x;
    int b = g / DI_, d = g % DI_;
    float h = 0.f;
    for (int c = 0; c < NC_; c++) {
        size_t o = ((size_t)b * NC_ + c) * DI_ + d;
        h0buf[o] = h;
        h = cA[o] * h + cB[o];
    }
    ns[(size_t)b * DI_ + d] = h;
}

// ---------------- Scan phase 3: recompute local scan, write hs bf16 ----------------
__global__ __launch_bounds__(256) void scan_phase3(
    const ushort_t* __restrict__ zb, const ushort_t* __restrict__ hb,
    const float* __restrict__ h0buf, ushort_t* __restrict__ hs)
{
    int d = blockIdx.x * 256 + threadIdx.x;
    int c = blockIdx.y, b = blockIdx.z;
    size_t base = ((size_t)b * S_ + (size_t)c * CL_) * DI_ + d;
    float h = h0buf[((size_t)b * NC_ + c) * DI_ + d];
    for (int t = 0; t < CL_; t++) {
        float z = bf2f(zb[base + (size_t)t * DI_]);
        float ht = bf2f(hb[base + (size_t)t * DI_]);
        h = (1.f - z) * h + z * ht;
        hs[base + (size_t)t * DI_] = f2bf(h);
    }
}

extern "C" void kernel_launch(void* const* d_in, const int* in_sizes, int n_in,
                              void* d_out, int out_size, void* d_ws, size_t ws_size,
                              hipStream_t stream)
{
    const float* in    = (const float*)d_in[0];
    const float* nw    = (const float*)d_in[1];
    const float* rw    = (const float*)d_in[2];
    const float* rb    = (const float*)d_in[3];
    const float* w_in  = (const float*)d_in[4];
    const float* b_in  = (const float*)d_in[5];
    const float* w_out = (const float*)d_in[6];
    const float* b_out = (const float*)d_in[7];
    float* out = (float*)d_out;

    char* ws = (char*)d_ws;
    size_t off = 0;
    auto nxt = [&](size_t bytes) -> void* {
        void* p = ws + off;
        off += (bytes + 255) & ~(size_t)255;
        return p;
    };
    ushort_t* xbf    = (ushort_t*)nxt((size_t)B_ * S_ * H_ * 2);
    ushort_t* wi_t   = (ushort_t*)nxt((size_t)B_ * DI2_ * H_ * 2);
    ushort_t* wo_t   = (ushort_t*)nxt((size_t)B_ * H_ * DI_ * 2);
    ushort_t* zbuf   = (ushort_t*)nxt((size_t)B_ * S_ * DI_ * 2);
    ushort_t* htbuf  = (ushort_t*)nxt((size_t)B_ * S_ * DI_ * 2);
    ushort_t* hsbuf  = (ushort_t*)nxt((size_t)B_ * S_ * DI_ * 2);
    float* partial   = (float*)nxt((size_t)B_ * 256 * H_ * 4);
    float* probs     = (float*)nxt((size_t)B_ * 3 * 4);
    float* bi        = (float*)nxt((size_t)B_ * DI2_ * 4);
    float* bo        = (float*)nxt((size_t)B_ * H_ * 4);
    float* cA        = (float*)nxt((size_t)B_ * NC_ * DI_ * 4);
    float* cB        = (float*)nxt((size_t)B_ * NC_ * DI_ * 4);
    float* h0buf     = (float*)nxt((size_t)B_ * NC_ * DI_ * 4);

    float* ns  = out + (size_t)B_ * S_ * H_;
    float* aux = ns + (size_t)B_ * DI_;

    rmsnorm_kernel<<<dim3(S_ / 16, B_), 256, 0, stream>>>(in, nw, xbf, partial);
    router_kernel<<<dim3(B_), 256, 0, stream>>>(partial, rw, rb, b_in, b_out, probs, bi, bo, aux);
    mix_kernel<<<dim3(H_ / 64, DI2_ / 64, B_), 256, 0, stream>>>(w_in, probs, wi_t, H_, DI2_);
    mix_kernel<<<dim3(DI_ / 64, H_ / 64, B_), 256, 0, stream>>>(w_out, probs, wo_t, DI_, H_);
    gemm_bt<0><<<dim3(S_ / 128, DI2_ / 128, B_), 256, 0, stream>>>(
        xbf, wi_t, S_, DI2_, H_, bi, nullptr, nullptr, htbuf, zbuf, DI_);
    scan_phase1<<<dim3(DI_ / 256, NC_, B_), 256, 0, stream>>>(zbuf, htbuf, cA, cB);
    scan_phase2<<<dim3((B_ * DI_) / 256), 256, 0, stream>>>(cA, cB, h0buf, ns);
    scan_phase3<<<dim3(DI_ / 256, NC_, B_), 256, 0, stream>>>(zbuf, htbuf, h0buf, hsbuf);
    gemm_bt<1><<<dim3(S_ / 128, H_ / 128, B_), 256, 0, stream>>>(
        hsbuf, wo_t, S_, H_, DI_, bo, in, out, nullptr, nullptr, DI_);
    (void)in_sizes; (void)n_in; (void)out_size; (void)ws_size;
}

// Round 2
// 436.166 us; speedup vs baseline: 1.0632x; 1.0632x over previous
//
#include <hip/hip_runtime.h>
#include <hip/hip_bf16.h>

#define B_  4
#define S_  4096
#define H_  1024
#define DI_ 1280
#define DI2_ 2560
#define E_  3
#define NC_ 64
#define CL_ 64
#define EPS_ 1e-6f

typedef unsigned short ushort_t;
typedef __attribute__((ext_vector_type(8))) __bf16 bf16x8;
typedef __attribute__((ext_vector_type(4))) float f32x4;

__device__ inline ushort_t f2bf(float f) {
    union { float f; unsigned u; } v; v.f = f;
    unsigned r = v.u + 0x7fffu + ((v.u >> 16) & 1u);
    return (ushort_t)(r >> 16);
}
__device__ inline float bf2f(ushort_t s) {
    union { unsigned u; float f; } v; v.u = ((unsigned)s) << 16;
    return v.f;
}
__device__ inline float sigmoidf_(float x) { return 1.0f / (1.0f + __expf(-x)); }

__device__ inline void gld16(const void* g, void* l) {
    __builtin_amdgcn_global_load_lds(
        (const __attribute__((address_space(1))) void*)g,
        (__attribute__((address_space(3))) void*)l, 16, 0, 0);
}

// ---------------- Kernel A: RMSNorm + pooled partials ----------------
__global__ __launch_bounds__(256) void rmsnorm_kernel(
    const float* __restrict__ in, const float* __restrict__ nw,
    ushort_t* __restrict__ xbf, float* __restrict__ partial)
{
    int g = blockIdx.x, b = blockIdx.y;
    int tid = threadIdx.x, lane = tid & 63, w = tid >> 6;
    int s0 = g * 16;
    const float4* inb = (const float4*)(in + ((size_t)b * S_ + s0) * H_);
    float4 rows[16];
    float ss[16];
#pragma unroll
    for (int r = 0; r < 16; r++) {
        float4 v = inb[(size_t)r * (H_ / 4) + tid];
        rows[r] = v;
        ss[r] = v.x * v.x + v.y * v.y + v.z * v.z + v.w * v.w;
    }
#pragma unroll
    for (int r = 0; r < 16; r++) {
        float s = ss[r];
        s += __shfl_down(s, 32); s += __shfl_down(s, 16); s += __shfl_down(s, 8);
        s += __shfl_down(s, 4);  s += __shfl_down(s, 2);  s += __shfl_down(s, 1);
        ss[r] = s;
    }
    __shared__ float red[16][4];
    __shared__ float scl[16];
    if (lane == 0) {
#pragma unroll
        for (int r = 0; r < 16; r++) red[r][w] = ss[r];
    }
    __syncthreads();
    if (tid < 16) {
        float t = red[tid][0] + red[tid][1] + red[tid][2] + red[tid][3];
        scl[tid] = rsqrtf(t * (1.0f / H_) + EPS_);
    }
    __syncthreads();
    float4 nw4 = ((const float4*)nw)[tid];
    float4 pacc = {0.f, 0.f, 0.f, 0.f};
    ushort_t* xrow = xbf + ((size_t)b * S_ + s0) * H_;
#pragma unroll
    for (int r = 0; r < 16; r++) {
        float sc = scl[r];
        float4 v = rows[r];
        v.x = v.x * sc * nw4.x; v.y = v.y * sc * nw4.y;
        v.z = v.z * sc * nw4.z; v.w = v.w * sc * nw4.w;
        ushort4 u; u.x = f2bf(v.x); u.y = f2bf(v.y); u.z = f2bf(v.z); u.w = f2bf(v.w);
        *(ushort4*)(xrow + (size_t)r * H_ + tid * 4) = u;
        pacc.x += v.x; pacc.y += v.y; pacc.z += v.z; pacc.w += v.w;
    }
    float4* pp = (float4*)(partial + ((size_t)(b * 256 + g)) * H_);
    pp[tid] = pacc;
}

// ---------------- Kernel B: router softmax + bias mixing + aux ----------------
__global__ __launch_bounds__(256) void router_kernel(
    const float* __restrict__ partial, const float* __restrict__ rw,
    const float* __restrict__ rb, const float* __restrict__ b_in,
    const float* __restrict__ b_out, float* __restrict__ probs,
    float* __restrict__ bi, float* __restrict__ bo, float* __restrict__ aux)
{
    int b = blockIdx.x;
    int tid = threadIdx.x, lane = tid & 63, w = tid >> 6;
    float4 acc = {0.f, 0.f, 0.f, 0.f};
    const float4* pp = (const float4*)partial;
    for (int g = 0; g < 256; g++) {
        float4 v = pp[((size_t)(b * 256 + g)) * (H_ / 4) + tid];
        acc.x += v.x; acc.y += v.y; acc.z += v.z; acc.w += v.w;
    }
    const float inv_s = 1.0f / (float)S_;
    float a4[4] = {acc.x * inv_s, acc.y * inv_s, acc.z * inv_s, acc.w * inv_s};
    float le[3] = {0.f, 0.f, 0.f};
    int h0 = tid * 4;
#pragma unroll
    for (int j = 0; j < 4; j++) {
        float p = a4[j];
        le[0] += p * rw[(size_t)(h0 + j) * 3 + 0];
        le[1] += p * rw[(size_t)(h0 + j) * 3 + 1];
        le[2] += p * rw[(size_t)(h0 + j) * 3 + 2];
    }
#pragma unroll
    for (int e = 0; e < 3; e++) {
        float s = le[e];
        s += __shfl_down(s, 32); s += __shfl_down(s, 16); s += __shfl_down(s, 8);
        s += __shfl_down(s, 4);  s += __shfl_down(s, 2);  s += __shfl_down(s, 1);
        le[e] = s;
    }
    __shared__ float red[4][3];
    __shared__ float pr[3];
    if (lane == 0) { red[w][0] = le[0]; red[w][1] = le[1]; red[w][2] = le[2]; }
    __syncthreads();
    if (tid == 0) {
        float l0 = red[0][0] + red[1][0] + red[2][0] + red[3][0] + rb[0];
        float l1 = red[0][1] + red[1][1] + red[2][1] + red[3][1] + rb[1];
        float l2 = red[0][2] + red[1][2] + red[2][2] + red[3][2] + rb[2];
        float m = fmaxf(l0, fmaxf(l1, l2));
        float e0 = __expf(l0 - m), e1 = __expf(l1 - m), e2 = __expf(l2 - m);
        float inv = 1.0f / (e0 + e1 + e2);
        pr[0] = e0 * inv; pr[1] = e1 * inv; pr[2] = e2 * inv;
    }
    __syncthreads();
    if (tid < 3) probs[b * 3 + tid] = pr[tid];
    float p0 = pr[0], p1 = pr[1], p2 = pr[2];
    for (int n = tid; n < DI2_; n += 256)
        bi[(size_t)b * DI2_ + n] = p0 * b_in[n] + p1 * b_in[DI2_ + n] + p2 * b_in[2 * DI2_ + n];
    for (int n = tid; n < H_; n += 256)
        bo[(size_t)b * H_ + n] = p0 * b_out[n] + p1 * b_out[H_ + n] + p2 * b_out[2 * H_ + n];
    if (b == 0 && tid == 0) *aux = 0.0f;
}

// ---------------- Kernel C: weight mix + transpose ----------------
__global__ __launch_bounds__(256) void mix_kernel(
    const float* __restrict__ wsrc, const float* __restrict__ probs,
    ushort_t* __restrict__ dst, int K, int N)
{
    int kt = blockIdx.x, nt = blockIdx.y, b = blockIdx.z;
    float p0 = probs[b * 3 + 0], p1 = probs[b * 3 + 1], p2 = probs[b * 3 + 2];
    __shared__ float T[64][65];
    int tid = threadIdx.x;
    int c = tid & 63, rr = tid >> 6;
    const float* w0 = wsrc;
    const float* w1 = wsrc + (size_t)K * N;
    const float* w2 = wsrc + 2 * (size_t)K * N;
    int k0 = kt * 64, n0 = nt * 64;
#pragma unroll
    for (int pass = 0; pass < 16; pass++) {
        int r = pass * 4 + rr;
        size_t idx = (size_t)(k0 + r) * N + n0 + c;
        T[r][c] = p0 * w0[idx] + p1 * w1[idx] + p2 * w2[idx];
    }
    __syncthreads();
    ushort_t* db = dst + (size_t)b * N * K;
#pragma unroll
    for (int pass = 0; pass < 16; pass++) {
        int j = pass * 4 + rr;
        db[(size_t)(n0 + j) * K + k0 + c] = f2bf(T[c][j]);
    }
}

// ---------------- GEMM: C(MxN) = A(MxK bf16) @ Bt(NxK bf16)^T ----------------
// Transposed accumulators: mfma(bfr, af) -> D rows = n, cols = m.
// Per lane: acc[mi][ni][r] covers n = nblk+wx*64+ni*16+q*4+r (consecutive in r),
//                            m = mblk+wy*64+mi*16+ml.
// XOR-swizzled LDS (key = (row>>1)&3 on 16B col-blocks) for conflict-free ds_read_b128.
template <int MODE>
__global__ __launch_bounds__(256, 2) void gemm_bt(
    const ushort_t* __restrict__ Aall, const ushort_t* __restrict__ Btall,
    int M, int N, int K,
    const float* __restrict__ biasAll,
    const float* __restrict__ resAll, float* __restrict__ outAll,
    ushort_t* __restrict__ htAll, ushort_t* __restrict__ zAll, int DIv)
{
    __shared__ ushort_t As[128 * 32];
    __shared__ ushort_t Bs[128 * 32];
    int b = blockIdx.z;
    const ushort_t* A = Aall + (size_t)b * M * K;
    const ushort_t* Bt = Btall + (size_t)b * N * K;
    int tid = threadIdx.x, lane = tid & 63, w = tid >> 6;
    int mblk = blockIdx.x * 128, nblk = blockIdx.y * 128;

    // staging: lane covers (srow = lane>>2, slot = lane&3), global col-block
    // xor-swizzled so the 4 lanes of a quad still read one 64B row segment.
    int srow = lane >> 2;
    int sblk = (lane & 3) ^ ((srow >> 1) & 3);
    int scol = sblk * 8;
    const ushort_t* ga0 = A + (size_t)(mblk + (w * 2 + 0) * 16 + srow) * K + scol;
    const ushort_t* ga1 = A + (size_t)(mblk + (w * 2 + 1) * 16 + srow) * K + scol;
    const ushort_t* gb0 = Bt + (size_t)(nblk + (w * 2 + 0) * 16 + srow) * K + scol;
    const ushort_t* gb1 = Bt + (size_t)(nblk + (w * 2 + 1) * 16 + srow) * K + scol;
    ushort_t* la0 = &As[(w * 2 + 0) * 512 + lane * 8];
    ushort_t* la1 = &As[(w * 2 + 1) * 512 + lane * 8];
    ushort_t* lb0 = &Bs[(w * 2 + 0) * 512 + lane * 8];
    ushort_t* lb1 = &Bs[(w * 2 + 1) * 512 + lane * 8];

    f32x4 acc[4][4] = {};
    int wy = w & 1, wx = w >> 1;
    int q = lane >> 4;
    int ml = lane & 15;
    // fragment read: row ml, want global k-block q -> LDS slot q ^ ((ml>>1)&3)
    int rblk = (q ^ ((ml >> 1) & 3)) * 8;
    int aoff0 = wy * 2048 + ml * 32 + rblk;
    int boff0 = wx * 2048 + ml * 32 + rblk;

    for (int k0 = 0; k0 < K; k0 += 32) {
        gld16(ga0, la0); gld16(ga1, la1);
        gld16(gb0, lb0); gld16(gb1, lb1);
        ga0 += 32; ga1 += 32; gb0 += 32; gb1 += 32;
        __syncthreads();
        bf16x8 af[4], bfr[4];
#pragma unroll
        for (int i = 0; i < 4; i++) af[i] = *(const bf16x8*)&As[aoff0 + i * 512];
#pragma unroll
        for (int i = 0; i < 4; i++) bfr[i] = *(const bf16x8*)&Bs[boff0 + i * 512];
#pragma unroll
        for (int mi = 0; mi < 4; mi++)
#pragma unroll
            for (int ni = 0; ni < 4; ni++)
                acc[mi][ni] = __builtin_amdgcn_mfma_f32_16x16x32_bf16(bfr[ni], af[mi], acc[mi][ni], 0, 0, 0);
        __syncthreads();
    }

    int nq = nblk + wx * 64 + q * 4;       // n base (4 consecutive per acc reg)
    const float* bias = biasAll + (size_t)b * N;
    if (MODE == 0) {
        bool isgate = (nblk >= DIv);
        ushort_t* dst = (isgate ? zAll : htAll) + (size_t)b * (size_t)M * DIv;
        int ncol0 = isgate ? (nq - DIv) : nq;
#pragma unroll
        for (int mi = 0; mi < 4; mi++) {
            int m = mblk + wy * 64 + mi * 16 + ml;
            ushort_t* drow = dst + (size_t)m * DIv;
#pragma unroll
            for (int ni = 0; ni < 4; ni++) {
                float4 bv = *(const float4*)&bias[nq + ni * 16];
                f32x4 a = acc[mi][ni];
                float v0 = a[0] + bv.x, v1 = a[1] + bv.y, v2 = a[2] + bv.z, v3 = a[3] + bv.w;
                float r0, r1, r2, r3;
                if (isgate) {
                    r0 = sigmoidf_(v0); r1 = sigmoidf_(v1); r2 = sigmoidf_(v2); r3 = sigmoidf_(v3);
                } else {
                    r0 = (v0 >= 0.f) ? (v0 + 0.5f) : sigmoidf_(v0);
                    r1 = (v1 >= 0.f) ? (v1 + 0.5f) : sigmoidf_(v1);
                    r2 = (v2 >= 0.f) ? (v2 + 0.5f) : sigmoidf_(v2);
                    r3 = (v3 >= 0.f) ? (v3 + 0.5f) : sigmoidf_(v3);
                }
                ushort4 u; u.x = f2bf(r0); u.y = f2bf(r1); u.z = f2bf(r2); u.w = f2bf(r3);
                *(ushort4*)&drow[ncol0 + ni * 16] = u;
            }
        }
    } else {
        const float* resb = resAll + (size_t)b * (size_t)M * N;
        float* outp = outAll + (size_t)b * (size_t)M * N;
#pragma unroll
        for (int mi = 0; mi < 4; mi++) {
            int m = mblk + wy * 64 + mi * 16 + ml;
            const float* rrow = resb + (size_t)m * N;
            float* orow = outp + (size_t)m * N;
#pragma unroll
            for (int ni = 0; ni < 4; ni++) {
                int n0 = nq + ni * 16;
                float4 bv = *(const float4*)&bias[n0];
                float4 rv = *(const float4*)&rrow[n0];
                f32x4 a = acc[mi][ni];
                float4 o;
                o.x = a[0] + bv.x + rv.x; o.y = a[1] + bv.y + rv.y;
                o.z = a[2] + bv.z + rv.z; o.w = a[3] + bv.w + rv.w;
                *(float4*)&orow[n0] = o;
            }
        }
    }
}

// ---------------- Scan phase 1: per-chunk affine composition ----------------
// grid (NC, B), block 320 (each thread: 4 consecutive d)
__global__ __launch_bounds__(320) void scan_phase1(
    const ushort_t* __restrict__ zb, const ushort_t* __restrict__ hb,
    float* __restrict__ cA, float* __restrict__ cB)
{
    int d0 = threadIdx.x * 4;
    int c = blockIdx.x, b = blockIdx.y;
    size_t base = ((size_t)b * S_ + (size_t)c * CL_) * DI_ + d0;
    float A[4] = {1.f, 1.f, 1.f, 1.f};
    float Bc[4] = {0.f, 0.f, 0.f, 0.f};
    for (int t = 0; t < CL_; t++) {
        ushort4 zv = *(const ushort4*)&zb[base + (size_t)t * DI_];
        ushort4 hv = *(const ushort4*)&hb[base + (size_t)t * DI_];
        float z[4] = {bf2f(zv.x), bf2f(zv.y), bf2f(zv.z), bf2f(zv.w)};
        float h[4] = {bf2f(hv.x), bf2f(hv.y), bf2f(hv.z), bf2f(hv.w)};
#pragma unroll
        for (int j = 0; j < 4; j++) {
            float a = 1.f - z[j];
            A[j] *= a;
            Bc[j] = a * Bc[j] + z[j] * h[j];
        }
    }
    size_t o = ((size_t)b * NC_ + c) * DI_ + d0;
    float4 av; av.x = A[0]; av.y = A[1]; av.z = A[2]; av.w = A[3];
    float4 bv; bv.x = Bc[0]; bv.y = Bc[1]; bv.z = Bc[2]; bv.w = Bc[3];
    *(float4*)&cA[o] = av;
    *(float4*)&cB[o] = bv;
}

// ---------------- Scan phase 2: sequential chunk scan + new_state ----------------
// grid (5), block 256: B*DI/4 = 1280 threads, each handles 4 d
__global__ __launch_bounds__(256) void scan_phase2(
    const float* __restrict__ cA, const float* __restrict__ cB,
    float* __restrict__ h0buf, float* __restrict__ ns)
{
    int g = blockIdx.x * 256 + threadIdx.x;       // 0..1279
    int b = g / (DI_ / 4), dq = g % (DI_ / 4);
    int d0 = dq * 4;
    float4 h = {0.f, 0.f, 0.f, 0.f};
    for (int c = 0; c < NC_; c++) {
        size_t o = ((size_t)b * NC_ + c) * DI_ + d0;
        *(float4*)&h0buf[o] = h;
        float4 a = *(const float4*)&cA[o];
        float4 bb = *(const float4*)&cB[o];
        h.x = a.x * h.x + bb.x; h.y = a.y * h.y + bb.y;
        h.z = a.z * h.z + bb.z; h.w = a.w * h.w + bb.w;
    }
    *(float4*)&ns[(size_t)b * DI_ + d0] = h;
}

// ---------------- Scan phase 3: recompute local scan, write hs bf16 ----------------
__global__ __launch_bounds__(320) void scan_phase3(
    const ushort_t* __restrict__ zb, const ushort_t* __restrict__ hb,
    const float* __restrict__ h0buf, ushort_t* __restrict__ hs)
{
    int d0 = threadIdx.x * 4;
    int c = blockIdx.x, b = blockIdx.y;
    size_t base = ((size_t)b * S_ + (size_t)c * CL_) * DI_ + d0;
    float4 h0 = *(const float4*)&h0buf[((size_t)b * NC_ + c) * DI_ + d0];
    float h[4] = {h0.x, h0.y, h0.z, h0.w};
    for (int t = 0; t < CL_; t++) {
        ushort4 zv = *(const ushort4*)&zb[base + (size_t)t * DI_];
        ushort4 hv = *(const ushort4*)&hb[base + (size_t)t * DI_];
        float z[4] = {bf2f(zv.x), bf2f(zv.y), bf2f(zv.z), bf2f(zv.w)};
        float ht[4] = {bf2f(hv.x), bf2f(hv.y), bf2f(hv.z), bf2f(hv.w)};
        ushort4 u;
        h[0] = (1.f - z[0]) * h[0] + z[0] * ht[0]; u.x = f2bf(h[0]);
        h[1] = (1.f - z[1]) * h[1] + z[1] * ht[1]; u.y = f2bf(h[1]);
        h[2] = (1.f - z[2]) * h[2] + z[2] * ht[2]; u.z = f2bf(h[2]);
        h[3] = (1.f - z[3]) * h[3] + z[3] * ht[3]; u.w = f2bf(h[3]);
        *(ushort4*)&hs[base + (size_t)t * DI_] = u;
    }
}

extern "C" void kernel_launch(void* const* d_in, const int* in_sizes, int n_in,
                              void* d_out, int out_size, void* d_ws, size_t ws_size,
                              hipStream_t stream)
{
    const float* in    = (const float*)d_in[0];
    const float* nw    = (const float*)d_in[1];
    const float* rw    = (const float*)d_in[2];
    const float* rb    = (const float*)d_in[3];
    const float* w_in  = (const float*)d_in[4];
    const float* b_in  = (const float*)d_in[5];
    const float* w_out = (const float*)d_in[6];
    const float* b_out = (const float*)d_in[7];
    float* out = (float*)d_out;

    char* ws = (char*)d_ws;
    size_t off = 0;
    auto nxt = [&](size_t bytes) -> void* {
        void* p = ws + off;
        off += (bytes + 255) & ~(size_t)255;
        return p;
    };
    ushort_t* xbf    = (ushort_t*)nxt((size_t)B_ * S_ * H_ * 2);
    ushort_t* wi_t   = (ushort_t*)nxt((size_t)B_ * DI2_ * H_ * 2);
    ushort_t* wo_t   = (ushort_t*)nxt((size_t)B_ * H_ * DI_ * 2);
    ushort_t* zbuf   = (ushort_t*)nxt((size_t)B_ * S_ * DI_ * 2);
    ushort_t* htbuf  = (ushort_t*)nxt((size_t)B_ * S_ * DI_ * 2);
    ushort_t* hsbuf  = (ushort_t*)nxt((size_t)B_ * S_ * DI_ * 2);
    float* partial   = (float*)nxt((size_t)B_ * 256 * H_ * 4);
    float* probs     = (float*)nxt((size_t)B_ * 3 * 4);
    float* bi        = (float*)nxt((size_t)B_ * DI2_ * 4);
    float* bo        = (float*)nxt((size_t)B_ * H_ * 4);
    float* cA        = (float*)nxt((size_t)B_ * NC_ * DI_ * 4);
    float* cB        = (float*)nxt((size_t)B_ * NC_ * DI_ * 4);
    float* h0buf     = (float*)nxt((size_t)B_ * NC_ * DI_ * 4);

    float* ns  = out + (size_t)B_ * S_ * H_;
    float* aux = ns + (size_t)B_ * DI_;

    rmsnorm_kernel<<<dim3(S_ / 16, B_), 256, 0, stream>>>(in, nw, xbf, partial);
    router_kernel<<<dim3(B_), 256, 0, stream>>>(partial, rw, rb, b_in, b_out, probs, bi, bo, aux);
    mix_kernel<<<dim3(H_ / 64, DI2_ / 64, B_), 256, 0, stream>>>(w_in, probs, wi_t, H_, DI2_);
    mix_kernel<<<dim3(DI_ / 64, H_ / 64, B_), 256, 0, stream>>>(w_out, probs, wo_t, DI_, H_);
    gemm_bt<0><<<dim3(S_ / 128, DI2_ / 128, B_), 256, 0, stream>>>(
        xbf, wi_t, S_, DI2_, H_, bi, nullptr, nullptr, htbuf, zbuf, DI_);
    scan_phase1<<<dim3(NC_, B_), 320, 0, stream>>>(zbuf, htbuf, cA, cB);
    scan_phase2<<<dim3(5), 256, 0, stream>>>(cA, cB, h0buf, ns);
    scan_phase3<<<dim3(NC_, B_), 320, 0, stream>>>(zbuf, htbuf, h0buf, hsbuf);
    gemm_bt<1><<<dim3(S_ / 128, H_ / 128, B_), 256, 0, stream>>>(
        hsbuf, wo_t, S_, H_, DI_, bo, in, out, nullptr, nullptr, DI_);
    (void)in_sizes; (void)n_in; (void)out_size; (void)ws_size;
}

// Round 3
// 428.127 us; speedup vs baseline: 1.0832x; 1.0188x over previous
//
#include <hip/hip_runtime.h>
#include <hip/hip_bf16.h>

#define B_  4
#define S_  4096
#define H_  1024
#define DI_ 1280
#define DI2_ 2560
#define E_  3
#define NC_ 64
#define CL_ 64
#define EPS_ 1e-6f

typedef unsigned short ushort_t;
typedef __attribute__((ext_vector_type(8))) __bf16 bf16x8;
typedef __attribute__((ext_vector_type(4))) float f32x4;

__device__ inline ushort_t f2bf(float f) {
    union { float f; unsigned u; } v; v.f = f;
    unsigned r = v.u + 0x7fffu + ((v.u >> 16) & 1u);
    return (ushort_t)(r >> 16);
}
__device__ inline float bf2f(ushort_t s) {
    union { unsigned u; float f; } v; v.u = ((unsigned)s) << 16;
    return v.f;
}
__device__ inline float sigmoidf_(float x) { return 1.0f / (1.0f + __expf(-x)); }

__device__ inline void gld16(const void* g, void* l) {
    __builtin_amdgcn_global_load_lds(
        (const __attribute__((address_space(1))) void*)g,
        (__attribute__((address_space(3))) void*)l, 16, 0, 0);
}

// ---------------- Kernel A: RMSNorm + pooled partials ----------------
__global__ __launch_bounds__(256) void rmsnorm_kernel(
    const float* __restrict__ in, const float* __restrict__ nw,
    ushort_t* __restrict__ xbf, float* __restrict__ partial)
{
    int g = blockIdx.x, b = blockIdx.y;
    int tid = threadIdx.x, lane = tid & 63, w = tid >> 6;
    int s0 = g * 16;
    const float4* inb = (const float4*)(in + ((size_t)b * S_ + s0) * H_);
    float4 rows[16];
    float ss[16];
#pragma unroll
    for (int r = 0; r < 16; r++) {
        float4 v = inb[(size_t)r * (H_ / 4) + tid];
        rows[r] = v;
        ss[r] = v.x * v.x + v.y * v.y + v.z * v.z + v.w * v.w;
    }
#pragma unroll
    for (int r = 0; r < 16; r++) {
        float s = ss[r];
        s += __shfl_down(s, 32); s += __shfl_down(s, 16); s += __shfl_down(s, 8);
        s += __shfl_down(s, 4);  s += __shfl_down(s, 2);  s += __shfl_down(s, 1);
        ss[r] = s;
    }
    __shared__ float red[16][4];
    __shared__ float scl[16];
    if (lane == 0) {
#pragma unroll
        for (int r = 0; r < 16; r++) red[r][w] = ss[r];
    }
    __syncthreads();
    if (tid < 16) {
        float t = red[tid][0] + red[tid][1] + red[tid][2] + red[tid][3];
        scl[tid] = rsqrtf(t * (1.0f / H_) + EPS_);
    }
    __syncthreads();
    float4 nw4 = ((const float4*)nw)[tid];
    float4 pacc = {0.f, 0.f, 0.f, 0.f};
    ushort_t* xrow = xbf + ((size_t)b * S_ + s0) * H_;
#pragma unroll
    for (int r = 0; r < 16; r++) {
        float sc = scl[r];
        float4 v = rows[r];
        v.x = v.x * sc * nw4.x; v.y = v.y * sc * nw4.y;
        v.z = v.z * sc * nw4.z; v.w = v.w * sc * nw4.w;
        ushort4 u; u.x = f2bf(v.x); u.y = f2bf(v.y); u.z = f2bf(v.z); u.w = f2bf(v.w);
        *(ushort4*)(xrow + (size_t)r * H_ + tid * 4) = u;
        pacc.x += v.x; pacc.y += v.y; pacc.z += v.z; pacc.w += v.w;
    }
    float4* pp = (float4*)(partial + ((size_t)(b * 256 + g)) * H_);
    pp[tid] = pacc;
}

// ---------------- Kernel A2: partial reduce 256 -> 8 groups ----------------
// grid (B, 8), block 256
__global__ __launch_bounds__(256) void reduce_kernel(
    const float* __restrict__ partial, float* __restrict__ partial2)
{
    int b = blockIdx.x, j = blockIdx.y, tid = threadIdx.x;
    float4 acc = {0.f, 0.f, 0.f, 0.f};
    const float4* pp = (const float4*)partial;
    for (int g = j * 32; g < j * 32 + 32; g++) {
        float4 v = pp[((size_t)(b * 256 + g)) * (H_ / 4) + tid];
        acc.x += v.x; acc.y += v.y; acc.z += v.z; acc.w += v.w;
    }
    ((float4*)partial2)[((size_t)(b * 8 + j)) * (H_ / 4) + tid] = acc;
}

// ---------------- Kernel B: router softmax + bias mixing (interleaved bi) ----------------
__global__ __launch_bounds__(256) void router_kernel(
    const float* __restrict__ partial2, const float* __restrict__ rw,
    const float* __restrict__ rb, const float* __restrict__ b_in,
    const float* __restrict__ b_out, float* __restrict__ probs,
    float* __restrict__ bi, float* __restrict__ bo, float* __restrict__ aux)
{
    int b = blockIdx.x;
    int tid = threadIdx.x, lane = tid & 63, w = tid >> 6;
    float4 acc = {0.f, 0.f, 0.f, 0.f};
    const float4* pp = (const float4*)partial2;
    for (int g = 0; g < 8; g++) {
        float4 v = pp[((size_t)(b * 8 + g)) * (H_ / 4) + tid];
        acc.x += v.x; acc.y += v.y; acc.z += v.z; acc.w += v.w;
    }
    const float inv_s = 1.0f / (float)S_;
    float a4[4] = {acc.x * inv_s, acc.y * inv_s, acc.z * inv_s, acc.w * inv_s};
    float le[3] = {0.f, 0.f, 0.f};
    int h0 = tid * 4;
#pragma unroll
    for (int j = 0; j < 4; j++) {
        float p = a4[j];
        le[0] += p * rw[(size_t)(h0 + j) * 3 + 0];
        le[1] += p * rw[(size_t)(h0 + j) * 3 + 1];
        le[2] += p * rw[(size_t)(h0 + j) * 3 + 2];
    }
#pragma unroll
    for (int e = 0; e < 3; e++) {
        float s = le[e];
        s += __shfl_down(s, 32); s += __shfl_down(s, 16); s += __shfl_down(s, 8);
        s += __shfl_down(s, 4);  s += __shfl_down(s, 2);  s += __shfl_down(s, 1);
        le[e] = s;
    }
    __shared__ float red[4][3];
    __shared__ float pr[3];
    if (lane == 0) { red[w][0] = le[0]; red[w][1] = le[1]; red[w][2] = le[2]; }
    __syncthreads();
    if (tid == 0) {
        float l0 = red[0][0] + red[1][0] + red[2][0] + red[3][0] + rb[0];
        float l1 = red[0][1] + red[1][1] + red[2][1] + red[3][1] + rb[1];
        float l2 = red[0][2] + red[1][2] + red[2][2] + red[3][2] + rb[2];
        float m = fmaxf(l0, fmaxf(l1, l2));
        float e0 = __expf(l0 - m), e1 = __expf(l1 - m), e2 = __expf(l2 - m);
        float inv = 1.0f / (e0 + e1 + e2);
        pr[0] = e0 * inv; pr[1] = e1 * inv; pr[2] = e2 * inv;
    }
    __syncthreads();
    if (tid < 3) probs[b * 3 + tid] = pr[tid];
    float p0 = pr[0], p1 = pr[1], p2 = pr[2];
    // bi in INTERLEAVED n-space: n=2d -> hid bias (b_in[.][d]), n=2d+1 -> gate bias (b_in[.][DI+d])
    for (int n = tid; n < DI2_; n += 256) {
        int d = n >> 1;
        int src = (n & 1) ? (DI_ + d) : d;
        bi[(size_t)b * DI2_ + n] = p0 * b_in[src] + p1 * b_in[DI2_ + src] + p2 * b_in[2 * DI2_ + src];
    }
    for (int n = tid; n < H_; n += 256)
        bo[(size_t)b * H_ + n] = p0 * b_out[n] + p1 * b_out[H_ + n] + p2 * b_out[2 * H_ + n];
    if (b == 0 && tid == 0) *aux = 0.0f;
}

// ---------------- Kernel C: w_out mix + transpose ----------------
// src: (E, K, N) fp32. dst: (B, N, K) bf16.  grid (K/64, N/64, B), block 256
__global__ __launch_bounds__(256) void mix_kernel(
    const float* __restrict__ wsrc, const float* __restrict__ probs,
    ushort_t* __restrict__ dst, int K, int N)
{
    int kt = blockIdx.x, nt = blockIdx.y, b = blockIdx.z;
    float p0 = probs[b * 3 + 0], p1 = probs[b * 3 + 1], p2 = probs[b * 3 + 2];
    __shared__ float T[64][65];
    int tid = threadIdx.x;
    int c = tid & 63, rr = tid >> 6;
    const float* w0 = wsrc;
    const float* w1 = wsrc + (size_t)K * N;
    const float* w2 = wsrc + 2 * (size_t)K * N;
    int k0 = kt * 64, n0 = nt * 64;
#pragma unroll
    for (int pass = 0; pass < 16; pass++) {
        int r = pass * 4 + rr;
        size_t idx = (size_t)(k0 + r) * N + n0 + c;
        T[r][c] = p0 * w0[idx] + p1 * w1[idx] + p2 * w2[idx];
    }
    __syncthreads();
    ushort_t* db = dst + (size_t)b * N * K;
#pragma unroll
    for (int pass = 0; pass < 16; pass++) {
        int j = pass * 4 + rr;
        db[(size_t)(n0 + j) * K + k0 + c] = f2bf(T[c][j]);
    }
}

// ---------------- Kernel C2: w_in mix + transpose, INTERLEAVED dst rows ----------------
// src: (E, H, 2*DI) fp32. dst: (B, DI2, H) bf16 where dst row 2d = hid col d, 2d+1 = gate col d.
// grid (H/64, DI/32, B), block 256
__global__ __launch_bounds__(256) void mix_in_kernel(
    const float* __restrict__ wsrc, const float* __restrict__ probs,
    ushort_t* __restrict__ dst)
{
    int kt = blockIdx.x, dt = blockIdx.y, b = blockIdx.z;
    float p0 = probs[b * 3 + 0], p1 = probs[b * 3 + 1], p2 = probs[b * 3 + 2];
    __shared__ float Th[64][33];
    __shared__ float Tg[64][33];
    int tid = threadIdx.x;
    int k0 = kt * 64, d0 = dt * 32;
    const float* w0 = wsrc;
    const float* w1 = wsrc + (size_t)H_ * DI2_;
    const float* w2 = wsrc + 2 * (size_t)H_ * DI2_;
    {
        int c = tid & 31, rr = tid >> 5;   // 8 rows/pass
#pragma unroll
        for (int pass = 0; pass < 8; pass++) {
            int r = pass * 8 + rr;
            size_t ih = (size_t)(k0 + r) * DI2_ + d0 + c;
            size_t ig = ih + DI_;
            Th[r][c] = p0 * w0[ih] + p1 * w1[ih] + p2 * w2[ih];
            Tg[r][c] = p0 * w0[ig] + p1 * w1[ig] + p2 * w2[ig];
        }
    }
    __syncthreads();
    ushort_t* db = dst + (size_t)b * DI2_ * H_;
    int n0i = d0 * 2;
    int c = tid & 63, rr = tid >> 6;
#pragma unroll
    for (int pass = 0; pass < 16; pass++) {
        int jj = pass * 4 + rr;            // dst row within tile (interleaved)
        int d = jj >> 1;
        float v = (jj & 1) ? Tg[c][d] : Th[c][d];
        db[(size_t)(n0i + jj) * H_ + k0 + c] = f2bf(v);
    }
}

// ---------------- GEMM: C(MxN) = A(MxK bf16) @ Bt(NxK bf16)^T ----------------
// BK=64 (two 32-wide sub-panels, one barrier pair per 64 K). Grouped tile order.
// Transposed acc: acc[mi][ni][r] -> n = nq+ni*16+r (consecutive), m = mblk+wy*64+mi*16+ml.
// MODE 0: Bt rows interleaved (2d=hid,2d+1=gate); epilogue -> zh stream of (ht,z) bf16 pairs.
// MODE 1: epilogue -> out fp32 (+bias+residual)
template <int MODE>
__global__ __launch_bounds__(256, 2) void gemm_bt(
    const ushort_t* __restrict__ Aall, const ushort_t* __restrict__ Btall,
    int M, int N, int K,
    const float* __restrict__ biasAll,
    const float* __restrict__ resAll, float* __restrict__ outAll,
    ushort_t* __restrict__ zhAll)
{
    __shared__ ushort_t As[2 * 128 * 32];
    __shared__ ushort_t Bs[2 * 128 * 32];
    int b = blockIdx.z;
    const ushort_t* A = Aall + (size_t)b * M * K;
    const ushort_t* Bt = Btall + (size_t)b * N * K;
    int tid = threadIdx.x, lane = tid & 63, w = tid >> 6;

    // grouped tile mapping (GROUP m-tiles per group, n fastest within group)
    int num_n = N >> 7;
    const int GROUP = 4;
    int gsz = GROUP * num_n;
    int gid = blockIdx.x / gsz, rem = blockIdx.x % gsz;
    int mt = gid * GROUP + (rem & (GROUP - 1));
    int nt = rem >> 2;
    int mblk = mt * 128, nblk = nt * 128;

    int srow = lane >> 2;
    int sblk = (lane & 3) ^ ((srow >> 1) & 3);
    int scol = sblk * 8;
    const ushort_t* ga0 = A + (size_t)(mblk + (w * 2 + 0) * 16 + srow) * K + scol;
    const ushort_t* ga1 = A + (size_t)(mblk + (w * 2 + 1) * 16 + srow) * K + scol;
    const ushort_t* gb0 = Bt + (size_t)(nblk + (w * 2 + 0) * 16 + srow) * K + scol;
    const ushort_t* gb1 = Bt + (size_t)(nblk + (w * 2 + 1) * 16 + srow) * K + scol;
    ushort_t* la0 = &As[(w * 2 + 0) * 512 + lane * 8];
    ushort_t* la1 = &As[(w * 2 + 1) * 512 + lane * 8];
    ushort_t* lb0 = &Bs[(w * 2 + 0) * 512 + lane * 8];
    ushort_t* lb1 = &Bs[(w * 2 + 1) * 512 + lane * 8];

    f32x4 acc[4][4] = {};
    int wy = w & 1, wx = w >> 1;
    int q = lane >> 4;
    int ml = lane & 15;
    int rblk = (q ^ ((ml >> 1) & 3)) * 8;
    int aoff0 = wy * 2048 + ml * 32 + rblk;
    int boff0 = wx * 2048 + ml * 32 + rblk;

    for (int k0 = 0; k0 < K; k0 += 64) {
        // stage both 32-wide sub-panels (panel p at LDS offset p*4096, global offset p*32)
        gld16(ga0, la0);       gld16(ga1, la1);
        gld16(gb0, lb0);       gld16(gb1, lb1);
        gld16(ga0 + 32, la0 + 4096); gld16(ga1 + 32, la1 + 4096);
        gld16(gb0 + 32, lb0 + 4096); gld16(gb1 + 32, lb1 + 4096);
        ga0 += 64; ga1 += 64; gb0 += 64; gb1 += 64;
        __syncthreads();
#pragma unroll
        for (int p = 0; p < 2; p++) {
            bf16x8 af[4], bfr[4];
#pragma unroll
            for (int i = 0; i < 4; i++) af[i] = *(const bf16x8*)&As[p * 4096 + aoff0 + i * 512];
#pragma unroll
            for (int i = 0; i < 4; i++) bfr[i] = *(const bf16x8*)&Bs[p * 4096 + boff0 + i * 512];
#pragma unroll
            for (int mi = 0; mi < 4; mi++)
#pragma unroll
                for (int ni = 0; ni < 4; ni++)
                    acc[mi][ni] = __builtin_amdgcn_mfma_f32_16x16x32_bf16(bfr[ni], af[mi], acc[mi][ni], 0, 0, 0);
        }
        __syncthreads();
    }

    int nq = nblk + wx * 64 + q * 4;
    const float* bias = biasAll + (size_t)b * N;
    if (MODE == 0) {
        // n interleaved: even n -> hid(d=n/2), odd n -> gate(d=n/2).
        // acc reg r: [v0=hid_d, v1=gate_d, v2=hid_{d+1}, v3=gate_{d+1}]
        ushort_t* dst = zhAll + (size_t)b * (size_t)M * N;
#pragma unroll
        for (int mi = 0; mi < 4; mi++) {
            int m = mblk + wy * 64 + mi * 16 + ml;
            ushort_t* drow = dst + (size_t)m * N;
#pragma unroll
            for (int ni = 0; ni < 4; ni++) {
                int n0 = nq + ni * 16;
                float4 bv = *(const float4*)&bias[n0];
                f32x4 a = acc[mi][ni];
                float h0 = a[0] + bv.x, z0 = a[1] + bv.y;
                float h1 = a[2] + bv.z, z1 = a[3] + bv.w;
                float ht0 = (h0 >= 0.f) ? (h0 + 0.5f) : sigmoidf_(h0);
                float ht1 = (h1 >= 0.f) ? (h1 + 0.5f) : sigmoidf_(h1);
                float zz0 = sigmoidf_(z0), zz1 = sigmoidf_(z1);
                ushort4 u; u.x = f2bf(ht0); u.y = f2bf(zz0); u.z = f2bf(ht1); u.w = f2bf(zz1);
                *(ushort4*)&drow[n0] = u;
            }
        }
    } else {
        const float* resb = resAll + (size_t)b * (size_t)M * N;
        float* outp = outAll + (size_t)b * (size_t)M * N;
#pragma unroll
        for (int mi = 0; mi < 4; mi++) {
            int m = mblk + wy * 64 + mi * 16 + ml;
            const float* rrow = resb + (size_t)m * N;
            float* orow = outp + (size_t)m * N;
#pragma unroll
            for (int ni = 0; ni < 4; ni++) {
                int n0 = nq + ni * 16;
                float4 bv = *(const float4*)&bias[n0];
                float4 rv = *(const float4*)&rrow[n0];
                f32x4 a = acc[mi][ni];
                float4 o;
                o.x = a[0] + bv.x + rv.x; o.y = a[1] + bv.y + rv.y;
                o.z = a[2] + bv.z + rv.z; o.w = a[3] + bv.w + rv.w;
                *(float4*)&orow[n0] = o;
            }
        }
    }
}

// ---------------- Scan phase 1: per-chunk affine composition ----------------
// zh: (S, DI, 2) bf16 pairs (ht, z). grid (NC, B), block 320 (4 d per thread)
__global__ __launch_bounds__(320) void scan_phase1(
    const ushort_t* __restrict__ zh, float* __restrict__ cA, float* __restrict__ cB)
{
    int d0 = threadIdx.x * 4;
    int c = blockIdx.x, b = blockIdx.y;
    const ushort_t* base = zh + ((size_t)b * S_ + (size_t)c * CL_) * DI2_ + d0 * 2;
    float A[4] = {1.f, 1.f, 1.f, 1.f};
    float Bc[4] = {0.f, 0.f, 0.f, 0.f};
    for (int t = 0; t < CL_; t++) {
        uint4 u = *(const uint4*)(base + (size_t)t * DI2_);
        unsigned uu[4] = {u.x, u.y, u.z, u.w};
#pragma unroll
        for (int j = 0; j < 4; j++) {
            float ht = bf2f((ushort_t)(uu[j] & 0xffff));
            float z  = bf2f((ushort_t)(uu[j] >> 16));
            float a = 1.f - z;
            A[j] *= a;
            Bc[j] = a * Bc[j] + z * ht;
        }
    }
    size_t o = ((size_t)b * NC_ + c) * DI_ + d0;
    float4 av; av.x = A[0]; av.y = A[1]; av.z = A[2]; av.w = A[3];
    float4 bv; bv.x = Bc[0]; bv.y = Bc[1]; bv.z = Bc[2]; bv.w = Bc[3];
    *(float4*)&cA[o] = av;
    *(float4*)&cB[o] = bv;
}

// ---------------- Scan phase 2: sequential chunk scan + new_state ----------------
__global__ __launch_bounds__(256) void scan_phase2(
    const float* __restrict__ cA, const float* __restrict__ cB,
    float* __restrict__ h0buf, float* __restrict__ ns)
{
    int g = blockIdx.x * 256 + threadIdx.x;       // 0..1279
    int b = g / (DI_ / 4), dq = g % (DI_ / 4);
    int d0 = dq * 4;
    float4 h = {0.f, 0.f, 0.f, 0.f};
    for (int c = 0; c < NC_; c++) {
        size_t o = ((size_t)b * NC_ + c) * DI_ + d0;
        *(float4*)&h0buf[o] = h;
        float4 a = *(const float4*)&cA[o];
        float4 bb = *(const float4*)&cB[o];
        h.x = a.x * h.x + bb.x; h.y = a.y * h.y + bb.y;
        h.z = a.z * h.z + bb.z; h.w = a.w * h.w + bb.w;
    }
    *(float4*)&ns[(size_t)b * DI_ + d0] = h;
}

// ---------------- Scan phase 3: recompute local scan, write hs bf16 ----------------
__global__ __launch_bounds__(320) void scan_phase3(
    const ushort_t* __restrict__ zh, const float* __restrict__ h0buf,
    ushort_t* __restrict__ hs)
{
    int d0 = threadIdx.x * 4;
    int c = blockIdx.x, b = blockIdx.y;
    const ushort_t* base = zh + ((size_t)b * S_ + (size_t)c * CL_) * DI2_ + d0 * 2;
    ushort_t* hbase = hs + ((size_t)b * S_ + (size_t)c * CL_) * DI_ + d0;
    float4 h0 = *(const float4*)&h0buf[((size_t)b * NC_ + c) * DI_ + d0];
    float h[4] = {h0.x, h0.y, h0.z, h0.w};
    for (int t = 0; t < CL_; t++) {
        uint4 u = *(const uint4*)(base + (size_t)t * DI2_);
        unsigned uu[4] = {u.x, u.y, u.z, u.w};
        ushort4 o;
#pragma unroll
        for (int j = 0; j < 4; j++) {
            float ht = bf2f((ushort_t)(uu[j] & 0xffff));
            float z  = bf2f((ushort_t)(uu[j] >> 16));
            h[j] = (1.f - z) * h[j] + z * ht;
        }
        o.x = f2bf(h[0]); o.y = f2bf(h[1]); o.z = f2bf(h[2]); o.w = f2bf(h[3]);
        *(ushort4*)(hbase + (size_t)t * DI_) = o;
    }
}

extern "C" void kernel_launch(void* const* d_in, const int* in_sizes, int n_in,
                              void* d_out, int out_size, void* d_ws, size_t ws_size,
                              hipStream_t stream)
{
    const float* in    = (const float*)d_in[0];
    const float* nw    = (const float*)d_in[1];
    const float* rw    = (const float*)d_in[2];
    const float* rb    = (const float*)d_in[3];
    const float* w_in  = (const float*)d_in[4];
    const float* b_in  = (const float*)d_in[5];
    const float* w_out = (const float*)d_in[6];
    const float* b_out = (const float*)d_in[7];
    float* out = (float*)d_out;

    char* ws = (char*)d_ws;
    size_t off = 0;
    auto nxt = [&](size_t bytes) -> void* {
        void* p = ws + off;
        off += (bytes + 255) & ~(size_t)255;
        return p;
    };
    ushort_t* xbf    = (ushort_t*)nxt((size_t)B_ * S_ * H_ * 2);
    ushort_t* wi_t   = (ushort_t*)nxt((size_t)B_ * DI2_ * H_ * 2);
    ushort_t* wo_t   = (ushort_t*)nxt((size_t)B_ * H_ * DI_ * 2);
    ushort_t* zhbuf  = (ushort_t*)nxt((size_t)B_ * S_ * DI2_ * 2);
    ushort_t* hsbuf  = (ushort_t*)nxt((size_t)B_ * S_ * DI_ * 2);
    float* partial   = (float*)nxt((size_t)B_ * 256 * H_ * 4);
    float* partial2  = (float*)nxt((size_t)B_ * 8 * H_ * 4);
    float* probs     = (float*)nxt((size_t)B_ * 3 * 4);
    float* bi        = (float*)nxt((size_t)B_ * DI2_ * 4);
    float* bo        = (float*)nxt((size_t)B_ * H_ * 4);
    float* cA        = (float*)nxt((size_t)B_ * NC_ * DI_ * 4);
    float* cB        = (float*)nxt((size_t)B_ * NC_ * DI_ * 4);
    float* h0buf     = (float*)nxt((size_t)B_ * NC_ * DI_ * 4);

    float* ns  = out + (size_t)B_ * S_ * H_;
    float* aux = ns + (size_t)B_ * DI_;

    rmsnorm_kernel<<<dim3(S_ / 16, B_), 256, 0, stream>>>(in, nw, xbf, partial);
    reduce_kernel<<<dim3(B_, 8), 256, 0, stream>>>(partial, partial2);
    router_kernel<<<dim3(B_), 256, 0, stream>>>(partial2, rw, rb, b_in, b_out, probs, bi, bo, aux);
    mix_in_kernel<<<dim3(H_ / 64, DI_ / 32, B_), 256, 0, stream>>>(w_in, probs, wi_t);
    mix_kernel<<<dim3(DI_ / 64, H_ / 64, B_), 256, 0, stream>>>(w_out, probs, wo_t, DI_, H_);
    gemm_bt<0><<<dim3((S_ / 128) * (DI2_ / 128), 1, B_), 256, 0, stream>>>(
        xbf, wi_t, S_, DI2_, H_, bi, nullptr, nullptr, zhbuf);
    scan_phase1<<<dim3(NC_, B_), 320, 0, stream>>>(zhbuf, cA, cB);
    scan_phase2<<<dim3(5), 256, 0, stream>>>(cA, cB, h0buf, ns);
    scan_phase3<<<dim3(NC_, B_), 320, 0, stream>>>(zhbuf, h0buf, hsbuf);
    gemm_bt<1><<<dim3((S_ / 128) * (H_ / 128), 1, B_), 256, 0, stream>>>(
        hsbuf, wo_t, S_, H_, DI_, bo, in, out, nullptr);
    (void)in_sizes; (void)n_in; (void)out_size; (void)ws_size;
}